// Round 3
// baseline (296.413 us; speedup 1.0000x reference)
//
#include <hip/hip_runtime.h>
#include <math.h>

#define BB 2
#define NN 2048
#define KK 30
#define V_DIM 213
#define E_DIM 480
#define NODES (BB*NN)
#define RPB 4                 // rows per block (share one register-cached Ca gather)
#define NBLK (NODES/RPB)

typedef unsigned long long u64;
typedef unsigned int u32;
typedef float v4f __attribute__((ext_vector_type(4)));

// ---------- small helpers ----------
__device__ __forceinline__ float sgnf(float x){ return (x>0.f)?1.f:((x<0.f)?-1.f:0.f); }

__device__ __forceinline__ void cross3(const float* a, const float* b, float* c){
  c[0]=a[1]*b[2]-a[2]*b[1];
  c[1]=a[2]*b[0]-a[0]*b[2];
  c[2]=a[0]*b[1]-a[1]*b[0];
}
__device__ __forceinline__ void norm3e(float* v){ // v / max(||v||, 1e-8)
  float n = sqrtf(v[0]*v[0]+v[1]*v[1]+v[2]*v[2]);
  float inv = 1.0f/fmaxf(n,1e-8f);
  v[0]*=inv; v[1]*=inv; v[2]*=inv;
}
__device__ __forceinline__ float dot3(const float* a, const float* b){
  return a[0]*b[0]+a[1]*b[1]+a[2]*b[2];
}

// Given atoms p[12]=N,Ca,C,O of a residue, produce full[30]:
// [0..11]=N,Ca,C,O  [12..14]=Cb  [15..17]=V0  [18..20]=V1  [21..29]=Q rows (b1,n0,b1xn0)
__device__ __forceinline__ void node_derived(const float* p, const float (*va)[3],
                                             float* full, int isLast){
  for(int i=0;i<12;i++) full[i]=p[i];
  float bv[3],cv[3],av[3];
  for(int c=0;c<3;c++){ bv[c]=p[3+c]-p[c]; cv[c]=p[6+c]-p[3+c]; }
  cross3(bv,cv,av);
  for(int c=0;c<3;c++)
    full[12+c] = -0.58273431f*av[c] + 0.56802827f*bv[c] - 0.54067466f*cv[c] + p[3+c];
  for(int i=0;i<2;i++)
    for(int c=0;c<3;c++)
      full[15+3*i+c] = va[i][0]*av[c] + va[i][1]*bv[c] + va[i][2]*cv[c] + p[3+c];
  if (isLast){
    for(int i=0;i<9;i++) full[21+i]=0.f;   // padded Q row for last node
  } else {
    float u0[3],u1[3];
    for(int c=0;c<3;c++){ u0[c]=bv[c]; u1[c]=cv[c]; }
    norm3e(u0); norm3e(u1);
    float n0[3]; cross3(u0,u1,n0); norm3e(n0);
    float b1[3]; for(int c=0;c<3;c++) b1[c]=u0[c]-u1[c];
    norm3e(b1);
    float c2[3]; cross3(b1,n0,c2);
    for(int c=0;c<3;c++){ full[21+c]=b1[c]; full[24+c]=n0[c]; full[27+c]=c2[c]; }
  }
}

// atom indices: N=0,Ca=1,C=2,O=3,Cb=4,V0=5,V1=6
__device__ __constant__ int c_epA[29] = {1,1,2,1,0,4,1,4,0,4,3,4,2,4,1,3,2,2,0,2,3,0,0,3,3, 5,6,6,5};
__device__ __constant__ int c_epB[29] = {1,2,1,0,1,1,4,0,4,3,4,2,4,4,3,1,2,0,2,3,2,0,3,0,3, 5,6,5,6};
__device__ __constant__ int c_npA[12] = {1,1,1,0,0,3,1,4,4,2,6,5};
__device__ __constant__ int c_npB[12] = {0,2,3,2,3,2,4,0,3,4,5,6};

#define NBIN 2048
#define BINSHIFT 21   // bin = float_bits >> 21 (sign0 + exp8 + mant2)

// ---------- quaternion tail ----------
__device__ __forceinline__ void edge_tail_quat(const float* own, const float* nbk, float* tl){
  float R[3][3];
  for(int i=0;i<3;i++)for(int l2=0;l2<3;l2++){
    float s=0.f;
    for(int j=0;j<3;j++) s += own[21+3*j+i]*nbk[21+3*j+l2];
    R[i][l2]=s;
  }
  float Rxx=R[0][0],Ryy=R[1][1],Rzz=R[2][2];
  float m0=0.5f*sqrtf(fabsf(1.f+Rxx-Ryy-Rzz));
  float m1=0.5f*sqrtf(fabsf(1.f-Rxx+Ryy-Rzz));
  float m2=0.5f*sqrtf(fabsf(1.f-Rxx-Ryy+Rzz));
  float qx=sgnf(R[2][1]-R[1][2])*m0;
  float qy=sgnf(R[0][2]-R[2][0])*m1;
  float qz=sgnf(R[1][0]-R[0][1])*m2;
  float w =0.5f*sqrtf(fmaxf(1.f+Rxx+Ryy+Rzz,0.f));
  float inv=1.f/fmaxf(sqrtf(qx*qx+qy*qy+qz*qz+w*w),1e-8f);
  tl[0]=qx*inv; tl[1]=qy*inv; tl[2]=qz*inv; tl[3]=w*inv;
}

// ---------- single dispatch: each block does RPB rows: topk -> derived -> V -> E ----
__global__ __launch_bounds__(256,4) void fused_kernel(const float* __restrict__ X,
                                                      const float* __restrict__ mask,
                                                      const float* __restrict__ vatoms,
                                                      float* __restrict__ outIdx,
                                                      float* __restrict__ outV,
                                                      float* __restrict__ outE){
  // overlays: phase A: bins(8K)+cand(16K)=24K ; phase BCD: ~37.2K
  __shared__ __align__(16) char smem[38144];
  __shared__ float wred[4];
  __shared__ u32 wsum[4];
  __shared__ int s_cutbin;
  __shared__ u32 s_m;
  __shared__ int jarr[RPB][KK];

  const int t = threadIdx.x;
  const int row0 = blockIdx.x * RPB;
  const int b = row0 / NN, n0 = row0 % NN;   // RPB rows always within one batch
  const int w = t>>6, l = t&63;

  const float* Xb = X + (size_t)b*NN*12;
  const float* mb = mask + (size_t)b*NN;

  u32* bins = (u32*)smem;                 // 8 KB (transposed: bin q at (q&7)*256+(q>>3))
  u64* cand = (u64*)(smem + NBIN*4);      // 16 KB

  // ===== register-cached Ca gather, shared across RPB rows =====
  float cax[8],cay[8],caz[8],mbv[8];
  #pragma unroll
  for (int s=0;s<8;s++){
    const int i = s*256+t;
    const float* p = Xb + (size_t)i*12;
    cax[s]=p[3]; cay[s]=p[4]; caz[s]=p[5];
    mbv[s]=mb[i];
  }

  // ===== phase A: top-k per row (bit-identical math to verified kernel) =====
  for (int r=0; r<RPB; ++r){
    const int n = n0 + r;
    const float cx=Xb[(size_t)n*12+3], cy=Xb[(size_t)n*12+4], cz=Xb[(size_t)n*12+5];
    const float mn=mb[n];

    for (int i=t;i<NBIN;i+=256) bins[i]=0;
    if (t==0) s_m=0;

    float dval[8];
    float lmax = -1e30f;
    #pragma unroll
    for (int s=0;s<8;s++){
      float dx=__fsub_rn(cax[s],cx), dy=__fsub_rn(cay[s],cy), dz=__fsub_rn(caz[s],cz);
      float ss=__fadd_rn(__fadd_rn(__fadd_rn(__fmul_rn(dx,dx),__fmul_rn(dy,dy)),
                                   __fmul_rn(dz,dz)), 1e-6f);
      float d = __fsqrt_rn(ss);
      float m2 = __fmul_rn(mbv[s], mn);
      float om = __fsub_rn(1.0f, m2);
      float D  = __fadd_rn(__fmul_rn(om,10000.0f), __fmul_rn(m2,d));
      dval[s]=D;
      lmax = fmaxf(lmax, D);
    }
    #pragma unroll
    for (int off=32; off; off>>=1) lmax = fmaxf(lmax, __shfl_xor(lmax, off));
    if (l==0) wred[w]=lmax;
    __syncthreads();                       // bins zeroed, s_m reset, wred ready

    const float srmax = fmaxf(fmaxf(wred[0],wred[1]), fmaxf(wred[2],wred[3]));
    const float radd = __fadd_rn(srmax, 1.0f);

    u32 keyb[8];
    #pragma unroll
    for (int s=0;s<8;s++){
      float m2 = __fmul_rn(mbv[s], mn);    // same value as verified kernel
      float om = __fsub_rn(1.0f, m2);
      float Dj = __fadd_rn(dval[s], __fmul_rn(om, radd));
      u32 kb = __float_as_uint(Dj);        // Dj >= 0 -> bits order-isomorphic
      keyb[s]=kb;
      u32 bin = kb >> BINSHIFT;
      atomicAdd(&bins[(bin&7)*256 + (bin>>3)], 1u);
    }
    __syncthreads();

    // scan: thread t owns logical bins [8t, 8t+8)
    u32 g8[8]; u32 lsum=0;
    #pragma unroll
    for (int j=0;j<8;j++){ g8[j]=bins[j*256+t]; lsum+=g8[j]; }
    u32 inc=lsum;
    #pragma unroll
    for (int off=1; off<64; off<<=1){
      u32 o = __shfl_up(inc, off);
      if (l >= off) inc += o;
    }
    if (l==63) wsum[w]=inc;
    __syncthreads();
    u32 waveoff=0;
    for (int ww=0; ww<w; ww++) waveoff += wsum[ww];
    u32 run = waveoff + inc - lsum;        // exclusive prefix of this 8-bin group
    #pragma unroll
    for (int j=0;j<8;j++){
      u32 c=g8[j];
      if (run < KK && run + c >= KK) s_cutbin = 8*t+j;   // unique writer
      run += c;
    }
    __syncthreads();
    const int cutbin = s_cutbin;

    // collect candidates (all bins <= cutbin); >=30 guaranteed
    #pragma unroll
    for (int s=0;s<8;s++){
      if ((int)(keyb[s] >> BINSHIFT) <= cutbin){
        u32 slot = atomicAdd(&s_m, 1u);
        cand[slot] = ((u64)keyb[s] << 32) | (u32)(s*256+t);
      }
    }
    __syncthreads();
    const int m = (int)s_m;

    // exact rank (keys unique: idx in low bits) -> scatter; order == lax.top_k
    for (int cix=t; cix<m; cix+=256){
      u64 mykey = cand[cix];
      int rank=0;
      for (int j=0;j<m;j++) rank += (cand[j] < mykey) ? 1 : 0;
      if (rank < KK){
        int idx = (int)(u32)(mykey & 0xffffffffu);
        outIdx[(size_t)(row0+r)*KK + rank] = (float)idx;
        jarr[r][rank] = idx;
      }
    }
    __syncthreads();   // cand/jarr done before next row resets s_m / re-zeroes bins
  }

  // ================= phase B: derived packets (overlay LDS) =================
  float* own   = (float*)smem;            // [RPB][32]
  float* nbp   = own + RPB*32;            // [RPB][KK][32]
  float* edist = nbp + RPB*KK*32;         // [RPB][872] (870 + pad)
  float* tailE = edist + RPB*872;         // [RPB][KK][16]
  float* dist_s= tailE + RPB*KK*16;       // [RPB][12]
  float* tail_s= dist_s + RPB*12;         // [RPB][24] (21 + pad)

  if (t < RPB*34){
    const int r = t/34, s = t-34*r;
    const int n = n0 + r;
    float va[2][3];
    for(int i=0;i<2;i++){
      float x=vatoms[3*i],y=vatoms[3*i+1],z=vatoms[3*i+2];
      float inv=1.f/sqrtf(x*x+y*y+z*z);
      va[i][0]=x*inv; va[i][1]=y*inv; va[i][2]=z*inv;
    }
    if (s < KK){
      const int j = jarr[r][s];
      float p[12];
      { const float* q = Xb + (size_t)j*12; for(int i=0;i<12;i++) p[i]=q[i]; }
      float full[30];
      node_derived(p, va, full, j==NN-1);
      for(int i=0;i<30;i++) nbp[(r*KK+s)*32+i]=full[i];
    } else if (s == 30){ // own packet
      float p[12];
      { const float* q = Xb + (size_t)n*12; for(int i=0;i<12;i++) p[i]=q[i]; }
      float full[30];
      node_derived(p, va, full, n==NN-1);
      for(int i=0;i<30;i++) own[r*32+i]=full[i];
    } else {
      // dihedral/angle r3 = s-31 (same math/op-order as verified kernel)
      const int r3 = s-31;
      float P[4][3];
      for (int o=0;o<4;o++){
        int mm = 3*n - 1 + r3 + o;
        if (mm>=0 && mm<3*NN){
          int res=mm/3, at=mm-3*res;
          const float* qq = Xb + (size_t)res*12 + at*3;
          P[o][0]=qq[0]; P[o][1]=qq[1]; P[o][2]=qq[2];
        } else { P[o][0]=P[o][1]=P[o][2]=0.f; }
      }
      float U[3][3];
      for (int o=0;o<3;o++){
        for(int c=0;c<3;c++) U[o][c]=P[o+1][c]-P[o][c];
        norm3e(U[o]);
      }
      float Dv=0.f, Av=0.f;
      int i3 = 3*n + r3;
      if (i3>=1 && i3<=3*NN-3){
        float n0v[3],n1v[3];
        cross3(U[0],U[1],n0v); norm3e(n0v);
        cross3(U[1],U[2],n1v); norm3e(n1v);
        float cosD = fminf(fmaxf(dot3(n0v,n1v), -1.f+1e-7f), 1.f-1e-7f);
        float v[3]; cross3(n0v,n1v,v); norm3e(v);
        float sg = -(v[0]*U[1][0]+v[1]*U[1][1]+v[2]*U[1][2]);
        Dv = sgnf(sg)*acosf(cosD);
        float cosA = fminf(fmaxf(dot3(U[0],U[1]), -1.f+1e-7f), 1.f-1e-7f);
        Av = acosf(cosA);
      }
      float* tl = tail_s + r*24;
      tl[0+r3]=cosf(Dv); tl[3+r3]=sinf(Dv);
      tl[6+r3]=cosf(Av); tl[9+r3]=sinf(Av);
    }
  }
  __syncthreads();   // own, nbp, dihedral tails ready

  // ================= phase C: distances + tails ============================
  if (t < RPB*KK){                       // 120 quaternions
    const int r=t/KK, k=t-KK*r;
    edge_tail_quat(&own[r*32], &nbp[(r*KK+k)*32], &tailE[(r*KK+k)*16]);
  } else if (t < RPB*KK + RPB*12){       // 48 node distances
    const int it=t-RPB*KK; const int r=it/12, c=it-12*r;
    const float* a=&own[r*32+3*c_npA[c]];
    const float* q=&own[r*32+3*c_npB[c]];
    float dx=a[0]-q[0], dy=a[1]-q[1], dz=a[2]-q[2];
    dist_s[r*12+c] = sqrtf(dx*dx+dy*dy+dz*dz+1e-6f);
  } else if (t < RPB*KK + RPB*12 + RPB*3){ // 12 V_direct items
    const int it=t-(RPB*KK+RPB*12); const int r=it/3, a2=it-3*r;
    const int aord[3]={0,2,3};
    int a=aord[a2];
    float d[3]; for(int c=0;c<3;c++) d[c]=own[r*32+3*a+c]-own[r*32+c];
    float dU[3];
    for(int i=0;i<3;i++)
      dU[i]=own[r*32+21+3*i]*d[0]+own[r*32+21+3*i+1]*d[1]+own[r*32+21+3*i+2]*d[2];
    norm3e(dU);
    for(int c=0;c<3;c++) tail_s[r*24+12+3*a2+c]=dU[c];
  }
  // E_direct: RPB*30*4 = 480 items
  for (int it=t; it<RPB*KK*4; it+=256){
    const int r=it/120, rem=it-120*r, k=rem>>2, a2=rem&3;
    const int aord[4]={1,0,2,3};   // Ca,N,C,O
    int a=aord[a2];
    float d[3]; for(int c=0;c<3;c++) d[c]=nbp[(r*KK+k)*32+3*a+c]-own[r*32+c];
    float dU[3];
    for(int i=0;i<3;i++)
      dU[i]=own[r*32+21+3*i]*d[0]+own[r*32+21+3*i+1]*d[1]+own[r*32+21+3*i+2]*d[2];
    norm3e(dU);
    tailE[(r*KK+k)*16+4+3*a2+0]=dU[0];
    tailE[(r*KK+k)*16+4+3*a2+1]=dU[1];
    tailE[(r*KK+k)*16+4+3*a2+2]=dU[2];
  }
  // edge distances: RPB*870 = 3480
  for (int g=t; g<RPB*KK*29; g+=256){
    const int r=g/870, gg=g-870*r, k=gg/29, c=gg-29*k;
    const float* a  = &own[r*32+3*c_epA[c]];
    const float* bq = &nbp[(r*KK+k)*32+3*c_epB[c]];
    float dx=a[0]-bq[0], dy=a[1]-bq[1], dz=a[2]-bq[2];
    edist[r*872 + k*29 + c] = sqrtf(dx*dx+dy*dy+dz*dz+1e-6f);
  }
  __syncthreads();   // dist_s, tail_s, edist, tailE ready

  // ================= phase D: output rows ==================================
  // V rows: RPB*213 floats, contiguous
  float* vb = outV + (size_t)row0*V_DIM;
  for (int g=t; g<RPB*V_DIM; g+=256){
    const int r=g/V_DIM, f=g-V_DIM*r;
    float val;
    if (f < 192){
      float D = dist_s[r*12 + (f>>4)];
      float t2 = (D - (20.0f/15.0f)*(float)(f&15))*0.8f;
      val = __expf(-t2*t2);
    } else {
      val = tail_s[r*24 + (f-192)];
    }
    vb[g]=val;
  }

  // E rows: RPB*30*480 floats = RPB*3600 quads, one contiguous NT stream
  v4f* eb = reinterpret_cast<v4f*>(outE + (size_t)row0*KK*E_DIM);
  for (int g=t; g<RPB*KK*120; g+=256){
    const int r=g/3600, q2=g-3600*r, k=q2/120, q=q2-120*k;
    v4f v;
    if (q < 116){
      float d = edist[r*872 + k*29 + (q>>2)];
      float r0 = (float)((q&3)*4);
      float t0 = (d - (20.0f/15.0f)*(r0+0.f))*0.8f;
      float t1 = (d - (20.0f/15.0f)*(r0+1.f))*0.8f;
      float t2 = (d - (20.0f/15.0f)*(r0+2.f))*0.8f;
      float t3 = (d - (20.0f/15.0f)*(r0+3.f))*0.8f;
      v.x=__expf(-t0*t0); v.y=__expf(-t1*t1); v.z=__expf(-t2*t2); v.w=__expf(-t3*t3);
    } else {
      const float* tl = &tailE[(r*KK+k)*16 + (q-116)*4];
      v.x=tl[0]; v.y=tl[1]; v.z=tl[2]; v.w=tl[3];
    }
    __builtin_nontemporal_store(v, &eb[g]);
  }
}

// ---------- launch ----------
extern "C" void kernel_launch(void* const* d_in, const int* in_sizes, int n_in,
                              void* d_out, int out_size, void* d_ws, size_t ws_size,
                              hipStream_t stream) {
  (void)in_sizes; (void)n_in; (void)out_size; (void)d_ws; (void)ws_size;
  const float* X    = (const float*)d_in[0];
  const float* mask = (const float*)d_in[1];
  const float* vat  = (const float*)d_in[2];
  float* out = (float*)d_out;

  float* outV   = out;
  float* outE   = out + (size_t)NODES*V_DIM;
  float* outIdx = out + (size_t)NODES*V_DIM + (size_t)NODES*KK*E_DIM;

  hipLaunchKernelGGL(fused_kernel, dim3(NBLK), dim3(256), 0, stream,
                     X, mask, vat, outIdx, outV, outE);
}